// Round 13
// baseline (763.271 us; speedup 1.0000x reference)
//
#include <hip/hip_runtime.h>
#include <hip/hip_fp16.h>
#include <math.h>

// ---------------- problem constants ----------------
static constexpr int   B_    = 4;
static constexpr int   N_    = 4096;
static constexpr int   BOX_  = 128;
static constexpr long long VOX_ = 1LL * BOX_ * BOX_ * BOX_;   // 2097152
static constexpr float EPS_IN_C  = 6.5f;
static constexpr float EPS_OUT_C = 79.0f;
static constexpr float QCONV_C   = 7046.52f;
static constexpr float KAPPA02_C = 0.8486f;
static constexpr float FOURPI_C  = 12.566370614359172f;

// ---------------- trilinear charge scatter (verified) ----------
__global__ void scatter_q_kernel(const float* __restrict__ coords,
                                 const float* __restrict__ params,
                                 const int*   __restrict__ num_atoms,
                                 float* __restrict__ q)
{
    int a = blockIdx.x * blockDim.x + threadIdx.x;
    if (a >= B_ * N_) return;
    int b = a >> 12;
    int n = a & (N_ - 1);
    if (n >= num_atoms[b]) return;

    float cx = coords[3 * a + 0];
    float cy = coords[3 * a + 1];
    float cz = coords[3 * a + 2];
    float chg = params[2 * a + 0] * QCONV_C;

    int ix0 = (int)floorf(cx), iy0 = (int)floorf(cy), iz0 = (int)floorf(cz);
    float fx = cx - (float)ix0, fy = cy - (float)iy0, fz = cz - (float)iz0;
    float wx[2] = {1.0f - fx, fx};
    float wy[2] = {1.0f - fy, fy};
    float wz[2] = {1.0f - fz, fz};

    float* qb = q + (long long)b * VOX_;
#pragma unroll
    for (int dx = 0; dx < 2; ++dx) {
        int ix = ix0 + dx;
        if ((unsigned)ix >= 128u) continue;
#pragma unroll
        for (int dy = 0; dy < 2; ++dy) {
            int iy = iy0 + dy;
            if ((unsigned)iy >= 128u) continue;
#pragma unroll
            for (int dz = 0; dz < 2; ++dz) {
                int iz = iz0 + dz;
                if ((unsigned)iz >= 128u) continue;
                atomicAdd(&qb[((long long)ix * 128 + iy) * 128 + iz],
                          chg * wx[dx] * wy[dy] * wz[dz]);
            }
        }
    }
}

// ---------------- eps gather v3 (round-8 verified): z-column blocks ---------
#define CAND_CAP 512
#define CHUNK 32

__global__ __launch_bounds__(512)
void eps_gather_v3(const float* __restrict__ coords,
                   const float* __restrict__ params,
                   const int*   __restrict__ num_atoms,
                   float* __restrict__ eps)   // [B][4][128^3]
{
    int bid = blockIdx.x;               // B * 16 * 16 blocks
    int b   = bid >> 8;
    int txi = (bid >> 4) & 15;
    int tyi = bid & 15;
    int tx = txi << 3, ty = tyi << 3;

    __shared__ float sx[CAND_CAP], sy[CAND_CAP], sz[CAND_CAP], sr[CAND_CAP];
    __shared__ float wts[CHUNK][9][8];
    __shared__ int  fidx[CAND_CAP];
    __shared__ int  s_cnt, s_fcnt;
    if (threadIdx.x == 0) s_cnt = 0;
    __syncthreads();

    int na = num_atoms[b];
    const float* cb = coords + (size_t)b * N_ * 3;
    const float* pb = params + (size_t)b * N_ * 2;

    float lox = (float)tx - 4.0f, hix = (float)tx + 12.5f;
    float loy = (float)ty - 4.0f, hiy = (float)ty + 12.5f;
    bool wx_ = (tx == 120), wy_ = (ty == 120);
    for (int n = threadIdx.x; n < na; n += 512) {
        float cx = cb[3 * n], cy = cb[3 * n + 1], cz = cb[3 * n + 2];
        bool okx = (cx >= lox && cx < hix) || (wx_ && cx < 4.5f);
        bool oky = (cy >= loy && cy < hiy) || (wy_ && cy < 4.5f);
        if (okx && oky) {
            int slot = atomicAdd(&s_cnt, 1);
            if (slot < CAND_CAP) {
                sx[slot] = cx; sy[slot] = cy; sz[slot] = cz;
                sr[slot] = pb[2 * n + 1];
            }
        }
    }
    __syncthreads();
    int cnt = min(s_cnt, CAND_CAP);

    int lz = threadIdx.x & 7;
    int ly = (threadIdx.x >> 3) & 7;
    int lx = threadIdx.x >> 6;

    float* eb = eps + (size_t)b * 4 * VOX_;

    for (int tzi = 0; tzi < 16; ++tzi) {
        int tz = tzi << 3;

        __syncthreads();
        if (threadIdx.x == 0) s_fcnt = 0;
        __syncthreads();
        {
            float loz = (float)tz - 4.0f, hiz = (float)tz + 12.5f;
            bool wz_ = (tz == 120);
            for (int i = threadIdx.x; i < cnt; i += 512) {
                float cz = sz[i];
                if ((cz >= loz && cz < hiz) || (wz_ && cz < 4.5f)) {
                    int s = atomicAdd(&s_fcnt, 1);
                    fidx[s] = i;
                }
            }
        }
        __syncthreads();
        int fcnt = s_fcnt;

        float r0 = 0.0f, r1 = 0.0f, r2 = 0.0f, r3 = 0.0f;

        for (int k0 = 0; k0 < fcnt; k0 += CHUNK) {
            int nC = min(CHUNK, fcnt - k0);
            __syncthreads();
            for (int w = threadIdx.x; w < nC * 72; w += 512) {
                int ka  = w / 72;
                int rem = w - ka * 72;
                int vi  = rem >> 3;
                int pos = rem & 7;
                int axis = vi / 3, var = vi - axis * 3;
                int k = fidx[k0 + ka];
                float c     = (axis == 0) ? sx[k] : (axis == 1) ? sy[k] : sz[k];
                int   torig = (axis == 0) ? tx    : (axis == 1) ? ty    : tz;
                float r = sr[k];
                float sig = (var == 2) ? (r + 1.0f) * 0.5f : (r + 1.4f) * 0.5f;
                float off = (var == 0) ? 0.0f : 0.5f;
                float inv2s2 = 1.0f / (2.0f * sig * sig);
                int i = torig + pos;
                int base = (int)floorf(c - off) - 4;
                float wv = 0.0f;
                if ((unsigned)(i - base) <= 8u) {
                    float d = (float)i + off - c;
                    wv = expf(-d * d * inv2s2);
                } else if ((unsigned)(i - 128 - base) <= 8u) {
                    float d = (float)(i - 128) + off - c;
                    wv = expf(-d * d * inv2s2);
                }
                wts[ka][vi][pos] = wv;
            }
            __syncthreads();
            for (int ka = 0; ka < nC; ++ka) {
                float xE0 = wts[ka][0][lx], xE5 = wts[ka][1][lx], xI5 = wts[ka][2][lx];
                float yE0 = wts[ka][3][ly], yE5 = wts[ka][4][ly], yI5 = wts[ka][5][ly];
                float zE0 = wts[ka][6][lz], zE5 = wts[ka][7][lz], zI5 = wts[ka][8][lz];
                r0 += xE5 * yE0 * zE0;
                r1 += xE0 * yE5 * zE0;
                r2 += xE0 * yE0 * zE5;
                r3 += xI5 * yI5 * zI5;
            }
        }

        int ix = tx + lx, iy = ty + ly, iz = tz + lz;
        size_t sp = ((size_t)ix * 128 + iy) * 128 + iz;
        eb[sp]                    = EPS_OUT_C + (EPS_IN_C - EPS_OUT_C) * fminf(fmaxf(r0, 0.0f), 1.0f);
        eb[sp + (size_t)VOX_]     = EPS_OUT_C + (EPS_IN_C - EPS_OUT_C) * fminf(fmaxf(r1, 0.0f), 1.0f);
        eb[sp + (size_t)VOX_ * 2] = EPS_OUT_C + (EPS_IN_C - EPS_OUT_C) * fminf(fmaxf(r2, 0.0f), 1.0f);
        eb[sp + (size_t)VOX_ * 3] = EPS_OUT_C + (EPS_IN_C - EPS_OUT_C) * fminf(fmaxf(r3, 0.0f), 1.0f);
    }
}

// ---------------- coefficient pack v4: folds sweep 1 (phi_0 == 0) -----------
__global__ void coef_pack4(const float* __restrict__ eps,
                           const float* __restrict__ q,
                           uint4* __restrict__ coef,
                           float* __restrict__ phi1)
{
    int tid = blockIdx.x * blockDim.x + threadIdx.x;
    size_t g4 = (size_t)tid * 4;
    int b  = (int)(g4 >> 21);
    size_t sp = g4 & (size_t)(VOX_ - 1);
    int x  = (int)(sp >> 14);
    int y  = (int)((sp >> 7) & 127);
    int z4 = (int)(sp & 127);

    const float* E = eps + (size_t)b * 4 * (size_t)VOX_;
    float4 ex4 = *reinterpret_cast<const float4*>(E + sp);
    float4 ey4 = *reinterpret_cast<const float4*>(E + sp + (size_t)VOX_);
    float4 ez4 = *reinterpret_cast<const float4*>(E + sp + (size_t)VOX_ * 2);
    float4 ek4 = *reinterpret_cast<const float4*>(E + sp + (size_t)VOX_ * 3);
    float4 eo  = make_float4(EPS_OUT_C, EPS_OUT_C, EPS_OUT_C, EPS_OUT_C);
    float4 exm4 = (x > 0) ? *reinterpret_cast<const float4*>(E + sp - 16384) : eo;
    float4 eym4 = (y > 0) ? *reinterpret_cast<const float4*>(E + sp + (size_t)VOX_ - 128) : eo;
    float ezm0  = (z4 > 0) ? E[sp + (size_t)VOX_ * 2 - 1] : EPS_OUT_C;
    float4 q4  = *reinterpret_cast<const float4*>(q + g4);

    float exA[4]  = {ex4.x, ex4.y, ex4.z, ex4.w};
    float eyA[4]  = {ey4.x, ey4.y, ey4.z, ey4.w};
    float ezA[4]  = {ez4.x, ez4.y, ez4.z, ez4.w};
    float ekA[4]  = {ek4.x, ek4.y, ek4.z, ek4.w};
    float exmA[4] = {exm4.x, exm4.y, exm4.z, exm4.w};
    float eymA[4] = {eym4.x, eym4.y, eym4.z, eym4.w};
    float ezmA[4] = {ezm0, ez4.x, ez4.y, ez4.z};
    float qA[4]   = {q4.x, q4.y, q4.z, q4.w};

    float ph[4];
#pragma unroll
    for (int j = 0; j < 4; ++j) {
        float lam = (ekA[j] - EPS_IN_C) / (EPS_OUT_C - EPS_IN_C);
        lam = fminf(fmaxf(lam, 0.0f), 1.0f);
        float denom = exA[j] + exmA[j] + eyA[j] + eymA[j] + ezA[j] + ezmA[j]
                    + KAPPA02_C * lam;
        float rcp = 1.0f / denom;

        __half2 h01 = __floats2half2_rn(exA[j] * rcp, exmA[j] * rcp);
        __half2 h23 = __floats2half2_rn(eyA[j] * rcp, eymA[j] * rcp);
        __half2 h45 = __floats2half2_rn(ezA[j] * rcp, ezmA[j] * rcp);
        __half2 h67 = __floats2half2_rn(FOURPI_C * qA[j] * rcp, 0.0f);
        uint4 u;
        u.x = *(unsigned int*)&h01;
        u.y = *(unsigned int*)&h23;
        u.z = *(unsigned int*)&h45;
        u.w = *(unsigned int*)&h67;
        coef[g4 + j] = u;
        ph[j] = __half22float2(h67).x;
    }
    *reinterpret_cast<float4*>(phi1 + g4) = make_float4(ph[0], ph[1], ph[2], ph[3]);
}

// ---------------- fused 3-step Jacobi (round 13) ----------------------------
// Three cascaded sweeps per launch. 16x32 tile, SEG=16, 512 threads,
// 1024 blocks. Rings: P (phi, halo-3, 22x38), S1 (halo-2, 20x36),
// S2 (halo-1, 18x34), CFB (band coef LDS, 208 entries/slice). Center coef
// rolls through 4 register generations. 3 barriers/x-iteration, each
// preceded by lgkmcnt(0) (verified f2p idiom). Bitwise == three v3 sweeps.
#define TY3 16
#define TZ3 32
#define R1Y 20
#define R1Z 36          // S1 ring (halo 2)
#define R2Y 18
#define R2Z 34          // S2 ring (halo 1)
#define PY3 22
#define PZ3 38          // phi tile (halo 3)
#define SEG3 16
#define NBND 208        // band1 (100) + band2 (108)

__global__ __launch_bounds__(512)
void jacobi_f3(const uint4* __restrict__ coef,
               const float* __restrict__ pin,
               float* __restrict__ pout)
{
    int bid = blockIdx.x;                 // 1024 blocks
    int xs = bid & 7;
    int zt = (bid >> 3) & 3;
    int yt = (bid >> 5) & 7;
    int b  = bid >> 8;
    int x_lo = xs * SEG3, x_hi = x_lo + SEG3 - 1;
    int y0 = yt * TY3, z0 = zt * TZ3;

    __shared__ float P [3][PY3 * PZ3];    // 836
    __shared__ float S1[3][R1Y * R1Z];    // 720
    __shared__ float S2[3][R2Y * R2Z];    // 612
    __shared__ uint4 CFB[3][NBND];

    int tid = threadIdx.x;
    int oy = tid >> 5, oz = tid & 31;     // center cell

    const uint4* cb = coef + (size_t)b * VOX_;
    const float* pb = pin  + (size_t)b * VOX_;
    float*       ob = pout + (size_t)b * VOX_;

    // ---- center maps ----
    int off_c = (y0 + oy) * 128 + (z0 + oz);
    int i2_c  = (oy + 1) * R2Z + (oz + 1);
    int i1_c  = (oy + 2) * R1Z + (oz + 2);
    int ip_c  = (oy + 3) * PZ3 + (oz + 3);

    // ---- band maps (S1 ring coords r1y,r1z) ----
    // tids 0..99  : band1 (outer ring of S2 tile, r2y/r2z) -> r1 = r2+1
    // tids 100..207: band2 (outer ring of S1 tile)
    bool hasB = (tid < NBND);
    bool isB1 = (tid < 100);
    int r2y = 0, r2z = 0, r1y = 0, r1z = 0;
    if (tid < 34)        { r2y = 0;  r2z = tid; }
    else if (tid < 68)   { r2y = 17; r2z = tid - 34; }
    else if (tid < 100)  { int t = tid - 68; r2y = 1 + (t >> 1); r2z = (t & 1) ? 33 : 0; }
    if (isB1) { r1y = r2y + 1; r1z = r2z + 1; }
    else if (hasB) {
        int t2 = tid - 100;
        if (t2 < 36)      { r1y = 0;  r1z = t2; }
        else if (t2 < 72) { r1y = 19; r1z = t2 - 36; }
        else              { int t = t2 - 72; r1y = 1 + (t >> 1); r1z = (t & 1) ? 35 : 0; }
    }
    int bnd_i1 = r1y * R1Z + r1z;
    int bnd_ip = (r1y + 1) * PZ3 + (r1z + 1);
    int bgy = y0 - 2 + r1y, bgz = z0 - 2 + r1z;
    bool bnd_ok = ((unsigned)bgy < 128u) && ((unsigned)bgz < 128u);
    int bnd_off = min(max(bgy, 0), 127) * 128 + min(max(bgz, 0), 127);
    int i2_b1 = r2y * R2Z + r2z;          // S2 index of band1 cell

    // ---- phi prefetch maps (836 entries: tid, tid+512) ----
    int p1_py = tid / PZ3, p1_pz = tid - p1_py * PZ3;
    int p1y = y0 - 3 + p1_py, p1z = z0 - 3 + p1_pz;
    bool p1_ok = ((unsigned)p1y < 128u) && ((unsigned)p1z < 128u);
    int p1_off = min(max(p1y, 0), 127) * 128 + min(max(p1z, 0), 127);
    int p2i = tid + 512;
    bool hasP2 = (p2i < PY3 * PZ3);
    int p2_py = p2i / PZ3, p2_pz = p2i - p2_py * PZ3;
    int p2y = y0 - 3 + p2_py, p2z = z0 - 3 + p2_pz;
    bool p2_ok = hasP2 && ((unsigned)p2y < 128u) && ((unsigned)p2z < 128u);
    int p2_off = min(max(p2y, 0), 127) * 128 + min(max(p2z, 0), 127);

    const float* ps0 = pb + (size_t)min(max(x_lo - 3, 0), 127) * 16384;
    float pfA = ps0[p1_off];
    float pfB = hasP2 ? ps0[p2_off] : 0.0f;
    uint4 z4 = make_uint4(0u, 0u, 0u, 0u);
    uint4 cfn = z4, cf_b1 = z4, cf_b2 = z4, cf_c = z4, cfbn = z4;

    for (int x = x_lo - 3; x <= x_hi + 3; ++x) {
        int m0 = (x + 6) % 3;             // slot(x) == slot(x-3)
        int m1 = (x + 5) % 3;             // slot(x-1) == slot(x-4)
        int m2 = (x + 4) % 3;             // slot(x-2)
        bool xin = (x >= 0 && x < 128);

        // ---- W: commit phi(x); stage band coef slice x-1 ----
        P[m0][tid] = (xin && p1_ok) ? pfA : 0.0f;
        if (hasP2) P[m0][p2i] = (xin && p2_ok) ? pfB : 0.0f;
        if (hasB) CFB[m1][tid] = cfbn;
        asm volatile("s_waitcnt lgkmcnt(0)" ::: "memory");
        __builtin_amdgcn_s_barrier();

        // ---- I: prefetch phi(x+1) ----
        if (x < x_hi + 3) {
            const float* ps = pb + (size_t)min(max(x + 1, 0), 127) * 16384;
            pfA = ps[p1_off];
            if (hasP2) pfB = ps[p2_off];
        }

        // ---- B1: S1(x-1) on halo-2 ring ----
        {
            int k1 = x - 1;
            if (k1 >= x_lo - 2 && k1 <= x_hi + 2) {
                bool kin = ((unsigned)k1 < 128u);
                {   // center
                    float v = 0.0f;
                    if (kin) {
                        const __half2* h = reinterpret_cast<const __half2*>(&cf_b1);
                        float2 a01 = __half22float2(h[0]);
                        float2 a23 = __half22float2(h[1]);
                        float2 a45 = __half22float2(h[2]);
                        float2 a67 = __half22float2(h[3]);
                        v = a01.x * P[m0][ip_c]
                          + a01.y * P[m2][ip_c]
                          + a23.x * P[m1][ip_c + PZ3]
                          + a23.y * P[m1][ip_c - PZ3]
                          + a45.x * P[m1][ip_c + 1]
                          + a45.y * P[m1][ip_c - 1]
                          + a67.x;
                    }
                    S1[m1][i1_c] = v;
                }
                if (hasB) {   // band1 + band2 cells of the ring
                    float v = 0.0f;
                    if (kin && bnd_ok) {
                        uint4 cu = CFB[m1][tid];
                        const __half2* h = reinterpret_cast<const __half2*>(&cu);
                        float2 a01 = __half22float2(h[0]);
                        float2 a23 = __half22float2(h[1]);
                        float2 a45 = __half22float2(h[2]);
                        float2 a67 = __half22float2(h[3]);
                        v = a01.x * P[m0][bnd_ip]
                          + a01.y * P[m2][bnd_ip]
                          + a23.x * P[m1][bnd_ip + PZ3]
                          + a23.y * P[m1][bnd_ip - PZ3]
                          + a45.x * P[m1][bnd_ip + 1]
                          + a45.y * P[m1][bnd_ip - 1]
                          + a67.x;
                    }
                    S1[m1][bnd_i1] = v;
                }
            }
        }
        // issue coef slice x loads (consumed B1(x+1), B2(x+2), C(x+3))
        if (x >= x_lo - 2 && x <= x_hi + 2) {
            const uint4* cs = cb + (size_t)min(max(x, 0), 127) * 16384;
            cfn = cs[off_c];
            if (hasB) cfbn = cs[bnd_off];
        }
        asm volatile("s_waitcnt lgkmcnt(0)" ::: "memory");
        __builtin_amdgcn_s_barrier();

        // ---- B2: S2(x-2) on halo-1 ring ----
        {
            int k2 = x - 2;
            if (k2 >= x_lo - 1 && k2 <= x_hi + 1) {
                bool kin = ((unsigned)k2 < 128u);
                {   // center
                    float v = 0.0f;
                    if (kin) {
                        const __half2* h = reinterpret_cast<const __half2*>(&cf_b2);
                        float2 a01 = __half22float2(h[0]);
                        float2 a23 = __half22float2(h[1]);
                        float2 a45 = __half22float2(h[2]);
                        float2 a67 = __half22float2(h[3]);
                        v = a01.x * S1[m1][i1_c]
                          + a01.y * S1[m0][i1_c]
                          + a23.x * S1[m2][i1_c + R1Z]
                          + a23.y * S1[m2][i1_c - R1Z]
                          + a45.x * S1[m2][i1_c + 1]
                          + a45.y * S1[m2][i1_c - 1]
                          + a67.x;
                    }
                    S2[m2][i2_c] = v;
                }
                if (isB1) {   // band1 cells of S2 ring
                    float v = 0.0f;
                    if (kin && bnd_ok) {
                        uint4 cu = CFB[m2][tid];
                        const __half2* h = reinterpret_cast<const __half2*>(&cu);
                        float2 a01 = __half22float2(h[0]);
                        float2 a23 = __half22float2(h[1]);
                        float2 a45 = __half22float2(h[2]);
                        float2 a67 = __half22float2(h[3]);
                        v = a01.x * S1[m1][bnd_i1]
                          + a01.y * S1[m0][bnd_i1]
                          + a23.x * S1[m2][bnd_i1 + R1Z]
                          + a23.y * S1[m2][bnd_i1 - R1Z]
                          + a45.x * S1[m2][bnd_i1 + 1]
                          + a45.y * S1[m2][bnd_i1 - 1]
                          + a67.x;
                    }
                    S2[m2][i2_b1] = v;
                }
            }
        }
        asm volatile("s_waitcnt lgkmcnt(0)" ::: "memory");
        __builtin_amdgcn_s_barrier();

        // ---- C: output xo = x-3 (center) ----
        {
            int xo = x - 3;
            if (xo >= x_lo) {
                const __half2* h = reinterpret_cast<const __half2*>(&cf_c);
                float2 a01 = __half22float2(h[0]);
                float2 a23 = __half22float2(h[1]);
                float2 a45 = __half22float2(h[2]);
                float2 a67 = __half22float2(h[3]);
                float out = a01.x * S2[m2][i2_c]
                          + a01.y * S2[m1][i2_c]
                          + a23.x * S2[m0][i2_c + R2Z]
                          + a23.y * S2[m0][i2_c - R2Z]
                          + a45.x * S2[m0][i2_c + 1]
                          + a45.y * S2[m0][i2_c - 1]
                          + a67.x;
                ob[(size_t)xo * 16384 + off_c] = out;
            }
        }
        // ---- roll coef generations ----
        cf_c  = cf_b2;
        cf_b2 = cf_b1;
        cf_b1 = cfn;
    }
}

// ---------------- Jacobi sweep v3: 4 z-voxels/thread (verified) -------------
__global__ void jacobi_v3(const uint4* __restrict__ coef,
                          const float* __restrict__ pin,
                          float* __restrict__ pout)
{
    int tid = blockIdx.x * blockDim.x + threadIdx.x;
    size_t g4 = (size_t)tid * 4;
    int z4 = (int)(g4 & 127);
    int y  = (int)((g4 >> 7) & 127);
    int x  = (int)((g4 >> 14) & 127);

    float4 pcv = *reinterpret_cast<const float4*>(pin + g4);
    float4 z4v = make_float4(0.f, 0.f, 0.f, 0.f);
    float4 pxpv = (x < 127) ? *reinterpret_cast<const float4*>(pin + g4 + 16384) : z4v;
    float4 pxmv = (x > 0)   ? *reinterpret_cast<const float4*>(pin + g4 - 16384) : z4v;
    float4 pypv = (y < 127) ? *reinterpret_cast<const float4*>(pin + g4 + 128)   : z4v;
    float4 pymv = (y > 0)   ? *reinterpret_cast<const float4*>(pin + g4 - 128)   : z4v;
    float zpE = (z4 < 124) ? pin[g4 + 4] : 0.0f;
    float zmE = (z4 > 0)   ? pin[g4 - 1] : 0.0f;

    float pxp[4] = {pxpv.x, pxpv.y, pxpv.z, pxpv.w};
    float pxm[4] = {pxmv.x, pxmv.y, pxmv.z, pxmv.w};
    float pyp[4] = {pypv.x, pypv.y, pypv.z, pypv.w};
    float pym[4] = {pymv.x, pymv.y, pymv.z, pymv.w};
    float pzp[4] = {pcv.y, pcv.z, pcv.w, zpE};
    float pzm[4] = {zmE, pcv.x, pcv.y, pcv.z};

    float out[4];
#pragma unroll
    for (int j = 0; j < 4; ++j) {
        uint4 cu = coef[g4 + j];
        const __half2* h = reinterpret_cast<const __half2*>(&cu);
        float2 a01 = __half22float2(h[0]);
        float2 a23 = __half22float2(h[1]);
        float2 a45 = __half22float2(h[2]);
        float2 a67 = __half22float2(h[3]);
        out[j] = a01.x * pxp[j] + a01.y * pxm[j]
               + a23.x * pyp[j] + a23.y * pym[j]
               + a45.x * pzp[j] + a45.y * pzm[j]
               + a67.x;
    }
    *reinterpret_cast<float4*>(pout + g4) = make_float4(out[0], out[1], out[2], out[3]);
}

// ---------------- Jacobi sweep v2 (fallback path, verified) ----------------
__global__ void jacobi_v2(const float* __restrict__ eps,
                          const float* __restrict__ q,
                          const float* __restrict__ pin,
                          float* __restrict__ pout)
{
    int bxy = blockIdx.x;
    int b = bxy >> 14;
    int x = (bxy >> 7) & 127;
    int y = bxy & 127;
    int z = threadIdx.x;

    size_t sp = ((size_t)x * 128 + y) * 128 + z;
    size_t g  = (size_t)b * (size_t)VOX_ + sp;
    const float* E = eps + (size_t)b * 4 * (size_t)VOX_;

    float ex = E[sp];
    float ey = E[sp + (size_t)VOX_];
    float ez = E[sp + (size_t)VOX_ * 2];
    float ek = E[sp + (size_t)VOX_ * 3];
    float exm = (x > 0) ? E[sp - 16384]                 : EPS_OUT_C;
    float eym = (y > 0) ? E[sp + (size_t)VOX_ - 128]    : EPS_OUT_C;
    float ezm = (z > 0) ? E[sp + (size_t)VOX_ * 2 - 1]  : EPS_OUT_C;

    float lam = (ek - EPS_IN_C) / (EPS_OUT_C - EPS_IN_C);
    lam = fminf(fmaxf(lam, 0.0f), 1.0f);
    float denom = ex + exm + ey + eym + ez + ezm + KAPPA02_C * lam;

    float pxp = (x < 127) ? pin[g + 16384] : 0.0f;
    float pxm = (x > 0)   ? pin[g - 16384] : 0.0f;
    float pyp = (y < 127) ? pin[g + 128]   : 0.0f;
    float pym = (y > 0)   ? pin[g - 128]   : 0.0f;
    float pzp = (z < 127) ? pin[g + 1]     : 0.0f;
    float pzm = (z > 0)   ? pin[g - 1]     : 0.0f;

    float num = ex * pxp + exm * pxm + ey * pyp + eym * pym
              + ez * pzp + ezm * pzm + FOURPI_C * q[g];
    pout[g] = num / denom;
}

// ---------------- launch ----------------
extern "C" void kernel_launch(void* const* d_in, const int* in_sizes, int n_in,
                              void* d_out, int out_size, void* d_ws, size_t ws_size,
                              hipStream_t stream)
{
    const float* coords    = (const float*)d_in[0];
    const float* params    = (const float*)d_in[1];
    const int*   num_atoms = (const int*)d_in[2];

    float* q   = (float*)d_out;                       // [B][128^3]
    float* eps = q + (size_t)B_ * VOX_;               // [B][4][128^3]
    float* phi = eps + (size_t)B_ * 4 * VOX_;         // [B][128^3]

    hipMemsetAsync(q, 0, (size_t)B_ * VOX_ * sizeof(float), stream);

    scatter_q_kernel<<<(B_ * N_ + 255) / 256, 256, 0, stream>>>(coords, params, num_atoms, q);
    eps_gather_v3<<<B_ * 16 * 16, 512, 0, stream>>>(coords, params, num_atoms, eps);

    size_t coefBytes = (size_t)B_ * VOX_ * sizeof(uint4);              // 134 MB
    size_t need = coefBytes + (size_t)B_ * VOX_ * sizeof(float);       // +33.5 MB

    if (ws_size >= need) {
        uint4* coefA = (uint4*)d_ws;
        float* tmp   = (float*)((char*)d_ws + coefBytes);
        // sweep 1 folded into coef_pack4 (phi_0 == 0): phi1 -> TMP
        coef_pack4<<<(int)(B_ * VOX_ / 4 / 256), 256, 0, stream>>>(eps, q, coefA, tmp);
        const float* cur = tmp;
        for (int it = 1; it <= 6; ++it) {           // 6 f3 = sweeps 2..19
            float* dst = (it & 1) ? phi : tmp;      // it=6 (even) -> tmp
            jacobi_f3<<<B_ * 8 * 8 * 4, 512, 0, stream>>>(coefA, cur, dst);
            cur = dst;
        }
        // sweep 20: single v3 sweep tmp -> phi (d_out)
        jacobi_v3<<<(int)(B_ * VOX_ / 4 / 256), 256, 0, stream>>>(coefA, cur, phi);
    } else {
        hipMemsetAsync(phi, 0, (size_t)B_ * VOX_ * sizeof(float), stream);
        float* tmp = (float*)d_ws;
        int jb = B_ * 128 * 128;
        const float* cur = phi;
        for (int it = 1; it <= 20; ++it) {
            float* dst = (it & 1) ? tmp : phi;
            jacobi_v2<<<jb, 128, 0, stream>>>(eps, q, cur, dst);
            cur = dst;
        }
    }
}